// Round 6
// baseline (253.206 us; speedup 1.0000x reference)
//
#include <hip/hip_runtime.h>
#include <math.h>

#define N_NODES 50000
#define N_EDGES 600000
#define DF 128
#define KK 256
#define DOUT 40
#define EPSN 1e-5f
#define NB1 196  // ceil(50000/256)

typedef __attribute__((ext_vector_type(8))) short sh8;   // 8 bf16 (4 VGPRs)
typedef __attribute__((ext_vector_type(4))) float f32x4;

__device__ __forceinline__ unsigned short f2b(float f) {  // fp32 -> bf16 RNE
  unsigned u = __builtin_bit_cast(unsigned, f);
  unsigned r = u + 0x7FFFu + ((u >> 16) & 1u);
  return (unsigned short)(r >> 16);
}
__device__ __forceinline__ float b2f(unsigned short b) {
  unsigned u = ((unsigned)b) << 16;
  return __builtin_bit_cast(float, u);
}

// ---------------------------------------------------------------------------
// CSR build
// ---------------------------------------------------------------------------
__global__ __launch_bounds__(256) void k_count(
    const int* __restrict__ ei, int* __restrict__ counts) {
  int e = blockIdx.x * 256 + threadIdx.x;
  if (e < N_EDGES) atomicAdd(&counts[ei[N_EDGES + e]], 1);
}

__global__ __launch_bounds__(256) void k_bsum(
    const int* __restrict__ counts, int* __restrict__ bsum) {
  int i = blockIdx.x * 256 + threadIdx.x;
  int v = (i < N_NODES) ? counts[i] : 0;
  #pragma unroll
  for (int m = 1; m < 64; m <<= 1) v += __shfl_xor(v, m);
  __shared__ int ws[4];
  if ((threadIdx.x & 63) == 0) ws[threadIdx.x >> 6] = v;
  __syncthreads();
  if (threadIdx.x == 0) bsum[blockIdx.x] = ws[0] + ws[1] + ws[2] + ws[3];
}

__global__ __launch_bounds__(256) void k_bscan(
    const int* __restrict__ bsum, int* __restrict__ bbase) {
  const int t = threadIdx.x, lane = t & 63, w = t >> 6;
  int v = (t < NB1) ? bsum[t] : 0;
  int s = v;
  #pragma unroll
  for (int off = 1; off < 64; off <<= 1) {
    int u = __shfl_up(s, off);
    if (lane >= off) s += u;
  }
  __shared__ int wtot[4];
  if (lane == 63) wtot[w] = s;
  __syncthreads();
  int add = 0;
  for (int k = 0; k < w; ++k) add += wtot[k];
  if (t < NB1) bbase[t] = s + add - v;  // exclusive
}

__global__ __launch_bounds__(256) void k_rowptr(
    const int* __restrict__ counts, const int* __restrict__ bbase,
    int* __restrict__ rowptr, int* __restrict__ cursor,
    float* __restrict__ invdeg) {
  const int i = blockIdx.x * 256 + threadIdx.x;
  const int lane = threadIdx.x & 63, w = threadIdx.x >> 6;
  int c = (i < N_NODES) ? counts[i] : 0;
  int s = c;
  #pragma unroll
  for (int off = 1; off < 64; off <<= 1) {
    int u = __shfl_up(s, off);
    if (lane >= off) s += u;
  }
  __shared__ int wtot[4];
  if (lane == 63) wtot[w] = s;
  __syncthreads();
  int add = bbase[blockIdx.x];
  for (int k = 0; k < w; ++k) add += wtot[k];
  if (i < N_NODES) {
    int excl = s - c + add;
    rowptr[i] = excl;
    cursor[i] = excl;
    invdeg[i] = 1.0f / (float)((c > 1) ? c : 1);
  }
  if (i == 0) rowptr[N_NODES] = N_EDGES;
}

__global__ __launch_bounds__(256) void k_fill(
    const int* __restrict__ ei, int* __restrict__ cursor, int* __restrict__ csr) {
  int e = blockIdx.x * 256 + threadIdx.x;
  if (e < N_EDGES) {
    int d = ei[N_EDGES + e];
    int p = atomicAdd(&cursor[d], 1);
    csr[p] = ei[e];
  }
}

// ---------------------------------------------------------------------------
// x (fp32) -> bf16 into x-half (cols 128:256) of Acat.
// ---------------------------------------------------------------------------
__global__ __launch_bounds__(256) void k_cvt_x(
    const float* __restrict__ x, unsigned* __restrict__ A) {
  int i = blockIdx.x * 256 + threadIdx.x;  // over N_NODES*64 float2s
  if (i >= N_NODES * 64) return;
  int n = i >> 6, p = i & 63;
  float2 v = ((const float2*)x)[i];
  A[(size_t)n * 128 + 64 + p] = (unsigned)f2b(v.x) | ((unsigned)f2b(v.y) << 16);
}

// ---------------------------------------------------------------------------
// Weight prep: WT[n][k] = bf16( k<128 ? Wl[k][n] : Wr[k-128][n] ), n<Npad.
// ---------------------------------------------------------------------------
__global__ __launch_bounds__(256) void k_cvt_w(
    const float* __restrict__ Wl, const float* __restrict__ Wr,
    unsigned short* __restrict__ WT, int Nact, int total) {
  int i = blockIdx.x * 256 + threadIdx.x;  // over Npad*256
  if (i >= total) return;
  int n = i >> 8, k = i & 255;
  float v = 0.0f;
  if (n < Nact) v = (k < DF) ? Wl[k * Nact + n] : Wr[(k - DF) * Nact + n];
  WT[i] = f2b(v);
}

// ---------------------------------------------------------------------------
// Gather-mean aggregation (bf16): one wave per dst node, 4-way ILP unroll.
// Reads x-half (uints 64:128) of Acat rows; writes msg-half (uints 0:64).
// ---------------------------------------------------------------------------
__global__ __launch_bounds__(256) void k_agg(
    unsigned* __restrict__ A, const int* __restrict__ rowptr,
    const int* __restrict__ csr, const float* __restrict__ invdeg) {
  const int node = (blockIdx.x * 256 + threadIdx.x) >> 6;
  const int lane = threadIdx.x & 63;
  if (node >= N_NODES) return;
  const int beg = rowptr[node], end = rowptr[node + 1];
  float ax = 0.f, ay = 0.f, bx = 0.f, by = 0.f;
  float cx = 0.f, cy = 0.f, dx = 0.f, dy = 0.f;
  int j = beg;
  for (; j + 4 <= end; j += 4) {
    int c0 = csr[j], c1 = csr[j + 1], c2 = csr[j + 2], c3 = csr[j + 3];
    unsigned p0 = A[(size_t)c0 * 128 + 64 + lane];
    unsigned p1 = A[(size_t)c1 * 128 + 64 + lane];
    unsigned p2 = A[(size_t)c2 * 128 + 64 + lane];
    unsigned p3 = A[(size_t)c3 * 128 + 64 + lane];
    ax += b2f((unsigned short)p0); ay += b2f((unsigned short)(p0 >> 16));
    bx += b2f((unsigned short)p1); by += b2f((unsigned short)(p1 >> 16));
    cx += b2f((unsigned short)p2); cy += b2f((unsigned short)(p2 >> 16));
    dx += b2f((unsigned short)p3); dy += b2f((unsigned short)(p3 >> 16));
  }
  for (; j < end; ++j) {
    unsigned p = A[(size_t)csr[j] * 128 + 64 + lane];
    ax += b2f((unsigned short)p); ay += b2f((unsigned short)(p >> 16));
  }
  ax += bx + cx + dx;
  ay += by + cy + dy;
  const float rd = invdeg[node];
  A[(size_t)node * 128 + lane] =
      (unsigned)f2b(ax * rd) | ((unsigned)f2b(ay * rd) << 16);
}

// ---------------------------------------------------------------------------
// MFMA GEMM [M=50000, K=256, N=128] + bias + LayerNorm + exact GELU.
// Block = 64 rows. A staged coalesced into swizzled LDS (32KB). B in regs:
// wave w owns cols [32w, 32w+32). LN partials exchanged via 2KB LDS.
// Output re-staged in LDS then stored as coalesced 16B chunks. In-place safe.
// ---------------------------------------------------------------------------
__global__ __launch_bounds__(256) void k_gemm128(
    const unsigned short* __restrict__ Acat, const unsigned short* __restrict__ WT,
    const float* __restrict__ bl, const float* __restrict__ g,
    const float* __restrict__ be, unsigned short* __restrict__ Adst) {
  __shared__ __align__(16) char lds[34816];        // 32KB A-tile + 2KB partials
  unsigned short* olds = (unsigned short*)lds;     // [64][136] bf16 (reuse)
  float2* pp = (float2*)(lds + 32768);             // [4][64] (s, sq)

  const int t = threadIdx.x;
  const int rw = blockIdx.x * 64;
  const int wave = t >> 6, lane = t & 63;
  const int lr = lane & 15, lg = lane >> 4;

  // --- stage A tile: 2048 x 16B chunks, coalesced, row-XOR swizzle ---
  #pragma unroll
  for (int it = 0; it < 8; ++it) {
    int id = it * 256 + t;
    int r = id >> 5, c = id & 31;
    int gr = rw + r; if (gr >= N_NODES) gr = N_NODES - 1;
    sh8 v = *(const sh8*)(Acat + (size_t)gr * KK + c * 8);
    unsigned off = (unsigned)((r * 512 + c * 16) ^ ((r & 7) << 4));
    *(sh8*)(lds + off) = v;
  }

  // --- B fragments in registers (L2-hot WT) ---
  sh8 Bfrag[2][8];
  #pragma unroll
  for (int fl = 0; fl < 2; ++fl) {
    const int n = wave * 32 + fl * 16 + lr;
    const sh8* Bp = (const sh8*)(WT + (size_t)n * KK + lg * 8);
    #pragma unroll
    for (int ks = 0; ks < 8; ++ks) Bfrag[fl][ks] = Bp[ks * 4];
  }
  const int col0 = wave * 32 + lr, col1 = col0 + 16;
  const float bc0 = bl[col0], bc1 = bl[col1];
  const float gv0 = g[col0], gv1 = g[col1];
  const float bev0 = be[col0], bev1 = be[col1];

  __syncthreads();

  f32x4 accs[4][2];
  #pragma unroll
  for (int rf = 0; rf < 4; ++rf)
    #pragma unroll
    for (int fl = 0; fl < 2; ++fl) accs[rf][fl] = (f32x4){0.f, 0.f, 0.f, 0.f};

  #pragma unroll
  for (int ks = 0; ks < 8; ++ks) {
    #pragma unroll
    for (int rf = 0; rf < 4; ++rf) {
      const int r = rf * 16 + lr;
      unsigned off = (unsigned)((r * 512 + ks * 64 + lg * 16) ^ ((r & 7) << 4));
      sh8 a = *(const sh8*)(lds + off);
      accs[rf][0] = __builtin_amdgcn_mfma_f32_16x16x32_bf16(a, Bfrag[0][ks], accs[rf][0], 0, 0, 0);
      accs[rf][1] = __builtin_amdgcn_mfma_f32_16x16x32_bf16(a, Bfrag[1][ks], accs[rf][1], 0, 0, 0);
    }
  }

  // --- bias + per-wave LN partials (sum, sumsq over this wave's 32 cols) ---
  #pragma unroll
  for (int rf = 0; rf < 4; ++rf) {
    float sv[4], qv[4];
    #pragma unroll
    for (int r = 0; r < 4; ++r) {
      float v0 = accs[rf][0][r] + bc0;
      float v1 = accs[rf][1][r] + bc1;
      accs[rf][0][r] = v0; accs[rf][1][r] = v1;
      sv[r] = v0 + v1; qv[r] = v0 * v0 + v1 * v1;
    }
    #pragma unroll
    for (int m = 1; m < 16; m <<= 1) {
      #pragma unroll
      for (int r = 0; r < 4; ++r) {
        sv[r] += __shfl_xor(sv[r], m);
        qv[r] += __shfl_xor(qv[r], m);
      }
    }
    if (lr == 0) {
      #pragma unroll
      for (int r = 0; r < 4; ++r)
        pp[wave * 64 + rf * 16 + lg * 4 + r] = make_float2(sv[r], qv[r]);
    }
  }
  __syncthreads();

  // --- finish LN + GELU, write bf16 into LDS out-stage ---
  #pragma unroll
  for (int rf = 0; rf < 4; ++rf) {
    #pragma unroll
    for (int r = 0; r < 4; ++r) {
      const int row = rf * 16 + lg * 4 + r;
      float2 q0 = pp[row], q1 = pp[64 + row], q2 = pp[128 + row], q3 = pp[192 + row];
      float mu = (q0.x + q1.x + q2.x + q3.x) * (1.0f / 128.0f);
      float var = (q0.y + q1.y + q2.y + q3.y) * (1.0f / 128.0f) - mu * mu;
      float rs = rsqrtf(var + EPSN);
      float xn0 = (accs[rf][0][r] - mu) * rs * gv0 + bev0;
      float xn1 = (accs[rf][1][r] - mu) * rs * gv1 + bev1;
      olds[row * 136 + col0] = f2b(0.5f * xn0 * (1.0f + erff(xn0 * 0.70710678118654752f)));
      olds[row * 136 + col1] = f2b(0.5f * xn1 * (1.0f + erff(xn1 * 0.70710678118654752f)));
    }
  }
  __syncthreads();

  // --- coalesced store: 1024 x 16B chunks into x-half of Adst rows ---
  #pragma unroll
  for (int it = 0; it < 4; ++it) {
    int id = it * 256 + t;
    int r = id >> 4, c = id & 15;
    int gr = rw + r;
    if (gr < N_NODES) {
      sh8 v = *(const sh8*)((char*)olds + r * 272 + c * 16);
      *(sh8*)(Adst + (size_t)gr * KK + 128 + c * 8) = v;
    }
  }
}

// ---------------------------------------------------------------------------
// Final MFMA GEMM [M=50000, K=256, N=48(pad 40)] + bias + log_softmax.
// Block = 64 rows; wave w owns rows [16w,16w+16), all 48 cols (B in regs).
// fp32 out re-staged in LDS, stored as coalesced float4.
// ---------------------------------------------------------------------------
__global__ __launch_bounds__(256) void k_gemm40(
    const unsigned short* __restrict__ Acat, const unsigned short* __restrict__ WT,
    const float* __restrict__ bl, float* __restrict__ out) {
  __shared__ __align__(16) char lds[43008];  // 32KB A-tile + 10KB f32 out-stage
  float* folds = (float*)(lds + 32768);      // [64][40]

  const int t = threadIdx.x;
  const int rw = blockIdx.x * 64;
  const int wave = t >> 6, lane = t & 63;
  const int lr = lane & 15, lg = lane >> 4;

  #pragma unroll
  for (int it = 0; it < 8; ++it) {
    int id = it * 256 + t;
    int r = id >> 5, c = id & 31;
    int gr = rw + r; if (gr >= N_NODES) gr = N_NODES - 1;
    sh8 v = *(const sh8*)(Acat + (size_t)gr * KK + c * 8);
    unsigned off = (unsigned)((r * 512 + c * 16) ^ ((r & 7) << 4));
    *(sh8*)(lds + off) = v;
  }

  sh8 Bfrag[3][8];
  #pragma unroll
  for (int f = 0; f < 3; ++f) {
    const int n = f * 16 + lr;
    const sh8* Bp = (const sh8*)(WT + (size_t)n * KK + lg * 8);
    #pragma unroll
    for (int ks = 0; ks < 8; ++ks) Bfrag[f][ks] = Bp[ks * 4];
  }

  __syncthreads();

  f32x4 accs[3];
  #pragma unroll
  for (int f = 0; f < 3; ++f) accs[f] = (f32x4){0.f, 0.f, 0.f, 0.f};

  #pragma unroll
  for (int ks = 0; ks < 8; ++ks) {
    const int r = wave * 16 + lr;
    unsigned off = (unsigned)((r * 512 + ks * 64 + lg * 16) ^ ((r & 7) << 4));
    sh8 a = *(const sh8*)(lds + off);
    #pragma unroll
    for (int f = 0; f < 3; ++f)
      accs[f] = __builtin_amdgcn_mfma_f32_16x16x32_bf16(a, Bfrag[f][ks], accs[f], 0, 0, 0);
  }

  const bool v2 = (lr < 8);
  float vals[3][4];
  #pragma unroll
  for (int f = 0; f < 3; ++f) {
    int col = lr + 16 * f;
    float bc = (col < DOUT) ? bl[col] : 0.0f;
    #pragma unroll
    for (int r = 0; r < 4; ++r) vals[f][r] = accs[f][r] + bc;
  }
  #pragma unroll
  for (int r = 0; r < 4; ++r) {
    float m = fmaxf(vals[0][r], vals[1][r]);
    if (v2) m = fmaxf(m, vals[2][r]);
    #pragma unroll
    for (int k = 1; k < 16; k <<= 1) m = fmaxf(m, __shfl_xor(m, k));
    float se = expf(vals[0][r] - m) + expf(vals[1][r] - m) +
               (v2 ? expf(vals[2][r] - m) : 0.0f);
    #pragma unroll
    for (int k = 1; k < 16; k <<= 1) se += __shfl_xor(se, k);
    float lse = m + logf(se);
    const int row = wave * 16 + lg * 4 + r;
    folds[row * 40 + lr]      = vals[0][r] - lse;
    folds[row * 40 + 16 + lr] = vals[1][r] - lse;
    if (v2) folds[row * 40 + 32 + lr] = vals[2][r] - lse;
  }
  __syncthreads();

  // --- coalesced store: 640 float4 chunks (10 per row) ---
  #pragma unroll
  for (int it = 0; it < 3; ++it) {
    int id = it * 256 + t;
    if (id < 640) {
      int r = (id * 6554) >> 16;   // id / 10
      int c = id - r * 10;
      int gr = rw + r;
      if (gr < N_NODES)
        *(float4*)(out + (size_t)gr * DOUT + c * 4) =
            *(const float4*)(folds + r * 40 + c * 4);
    }
  }
}

// ---------------------------------------------------------------------------
extern "C" void kernel_launch(void* const* d_in, const int* in_sizes, int n_in,
                              void* d_out, int out_size, void* d_ws, size_t ws_size,
                              hipStream_t stream) {
  const float* x   = (const float*)d_in[0];
  const int*   ei  = (const int*)d_in[1];
  const float* Wl0 = (const float*)d_in[2];
  const float* bl0 = (const float*)d_in[3];
  const float* Wr0 = (const float*)d_in[4];
  const float* Wl1 = (const float*)d_in[5];
  const float* bl1 = (const float*)d_in[6];
  const float* Wr1 = (const float*)d_in[7];
  const float* Wl2 = (const float*)d_in[8];
  const float* bl2 = (const float*)d_in[9];
  const float* Wr2 = (const float*)d_in[10];
  const float* g0  = (const float*)d_in[11];
  const float* be0 = (const float*)d_in[12];
  const float* g1  = (const float*)d_in[13];
  const float* be1 = (const float*)d_in[14];
  float* out = (float*)d_out;

  unsigned short* A   = (unsigned short*)d_ws;        // 50000*256 bf16
  unsigned short* WT0 = A + (size_t)N_NODES * KK;     // 128*256
  unsigned short* WT1 = WT0 + 128 * KK;               // 128*256
  unsigned short* WT2 = WT1 + 128 * KK;               // 48*256
  float* invdeg = (float*)(WT2 + 48 * KK);            // 50000
  int*   counts = (int*)(invdeg + N_NODES);           // 50000
  int*   rowptr = counts + N_NODES;                   // 50001
  int*   cursor = rowptr + N_NODES + 1;               // 50000
  int*   csr    = cursor + N_NODES;                   // 600000
  int*   bsum   = csr + N_EDGES;                      // NB1
  int*   bbase  = bsum + NB1;                         // NB1

  const int egrid = (N_EDGES + 255) / 256;    // 2344
  const int xgrid = (N_NODES * 64) / 256;     // 12500
  const int agrid = (N_NODES * 64) / 256;     // 12500 (wave per node)
  const int ggrid = (N_NODES + 63) / 64;      // 782

  // --- CSR build ---
  hipMemsetAsync(counts, 0, N_NODES * sizeof(int), stream);
  k_count<<<egrid, 256, 0, stream>>>(ei, counts);
  k_bsum<<<NB1, 256, 0, stream>>>(counts, bsum);
  k_bscan<<<1, 256, 0, stream>>>(bsum, bbase);
  k_rowptr<<<NB1, 256, 0, stream>>>(counts, bbase, rowptr, cursor, invdeg);
  k_fill<<<egrid, 256, 0, stream>>>(ei, cursor, csr);

  // --- one-time converts ---
  k_cvt_x<<<xgrid, 256, 0, stream>>>(x, (unsigned*)A);
  k_cvt_w<<<128, 256, 0, stream>>>(Wl0, Wr0, WT0, 128, 128 * KK);
  k_cvt_w<<<128, 256, 0, stream>>>(Wl1, Wr1, WT1, 128, 128 * KK);
  k_cvt_w<<<48, 256, 0, stream>>>(Wl2, Wr2, WT2, DOUT, 48 * KK);

  // --- Layer 0 ---
  k_agg<<<agrid, 256, 0, stream>>>((unsigned*)A, rowptr, csr, invdeg);
  k_gemm128<<<ggrid, 256, 0, stream>>>(A, WT0, bl0, g0, be0, A);

  // --- Layer 1 ---
  k_agg<<<agrid, 256, 0, stream>>>((unsigned*)A, rowptr, csr, invdeg);
  k_gemm128<<<ggrid, 256, 0, stream>>>(A, WT1, bl1, g1, be1, A);

  // --- Layer 2 ---
  k_agg<<<agrid, 256, 0, stream>>>((unsigned*)A, rowptr, csr, invdeg);
  k_gemm40<<<ggrid, 256, 0, stream>>>(A, WT2, bl2, out);
}